// Round 1
// baseline (780.242 us; speedup 1.0000x reference)
//
#include <hip/hip_runtime.h>
#include <hip/hip_bf16.h>

#define NNODE 8256
#define NEDGE 132096
#define DD 32
#define HIDN 128
#define NGR 32
#define PERG 258
#define BC 3   // centers per conv block (8256 = 3*2752)

// ---------------- node encoders: h[N][32] ----------------
__global__ __launch_bounds__(256) void k_encode(
    const float* __restrict__ pos, const float* __restrict__ vel,
    const float* __restrict__ nw1, const float* __restrict__ nb1,
    const float* __restrict__ nw2, const float* __restrict__ nb2,
    const float* __restrict__ vw1, const float* __restrict__ vb1,
    const float* __restrict__ vw2, const float* __restrict__ vb2,
    float* __restrict__ h)
{
    int i = blockIdx.x * 256 + threadIdx.x;
    if (i >= NNODE) return;
    float p0 = pos[i*3], p1 = pos[i*3+1], p2 = pos[i*3+2];
    float v0 = vel[i*3], v1 = vel[i*3+1], v2 = vel[i*3+2];
    float accP[16], accV[16];
    #pragma unroll
    for (int f = 0; f < 16; f++) { accP[f] = nb2[f]; accV[f] = vb2[f]; }
    for (int j = 0; j < HIDN; j++) {
        float hp = p0*nw1[j] + p1*nw1[128+j] + p2*nw1[256+j] + nb1[j];
        hp = hp >= 0.f ? hp : 0.2f*hp;
        float hv = v0*vw1[j] + v1*vw1[128+j] + v2*vw1[256+j] + vb1[j];
        hv = hv >= 0.f ? hv : 0.2f*hv;
        #pragma unroll
        for (int f = 0; f < 16; f++) {
            accP[f] += hp * nw2[j*16+f];
            accV[f] += hv * vw2[j*16+f];
        }
    }
    #pragma unroll
    for (int f = 0; f < 16; f++) {
        h[(size_t)i*DD + f]      = accP[f];
        h[(size_t)i*DD + 16 + f] = accV[f];
    }
}

// ---------------- per-edge dist, max-dist, degree count ----------------
__global__ __launch_bounds__(256) void k_edge1(
    const float* __restrict__ pos, const int* __restrict__ ei,
    float* __restrict__ dist, unsigned* __restrict__ maxd, int* __restrict__ deg)
{
    int e = blockIdx.x * 256 + threadIdx.x;
    float dd = 0.f;
    if (e < NEDGE) {
        int c = ei[e], n = ei[NEDGE + e];
        float dx = pos[c*3]   - pos[n*3];
        float dy = pos[c*3+1] - pos[n*3+1];
        float dz = pos[c*3+2] - pos[n*3+2];
        dd = sqrtf(dx*dx + dy*dy + dz*dz);
        dist[e] = dd;
        atomicAdd(&deg[c], 1);
    }
    // wave-level max then one atomic per wave
    #pragma unroll
    for (int o = 32; o > 0; o >>= 1) dd = fmaxf(dd, __shfl_down(dd, o, 64));
    if ((threadIdx.x & 63) == 0) atomicMax(maxd, __float_as_uint(dd));
}

// ---------------- exclusive scan of degrees -> CSR offsets ----------------
__global__ __launch_bounds__(1024) void k_scan(const int* __restrict__ deg, int* __restrict__ off)
{
    __shared__ int s[1024];
    int t = threadIdx.x;
    int base = t * 9;
    int loc[9]; int sum = 0;
    #pragma unroll
    for (int k = 0; k < 9; k++) {
        int i = base + k;
        int v = (i < NNODE) ? deg[i] : 0;
        loc[k] = sum; sum += v;
    }
    s[t] = sum; __syncthreads();
    for (int o = 1; o < 1024; o <<= 1) {
        int v = (t >= o) ? s[t - o] : 0;
        __syncthreads();
        s[t] += v;
        __syncthreads();
    }
    int pre = (t == 0) ? 0 : s[t-1];
    #pragma unroll
    for (int k = 0; k < 9; k++) {
        int i = base + k;
        if (i < NNODE) off[i] = pre + loc[k];
    }
    if (t == 1023) off[NNODE] = s[1023];
}

// ---------------- scatter edges into CSR order ----------------
__global__ __launch_bounds__(256) void k_scatter(
    const int* __restrict__ ei, const int* __restrict__ off,
    int* __restrict__ cursor, int* __restrict__ sN, int* __restrict__ sE)
{
    int e = blockIdx.x * 256 + threadIdx.x;
    if (e >= NEDGE) return;
    int c = ei[e];
    int p = off[c] + atomicAdd(&cursor[c], 1);
    sN[p] = ei[NEDGE + e];
    sE[p] = e;
}

// ---------------- z2[e][128] = relu(relu(w*W1+b1) @ W2 + b2) ----------------
// 4 waves/block, 8 edges/wave, each lane owns 2 output cols (float2)
__global__ __launch_bounds__(256) void k_z2(
    const float* __restrict__ dist, const unsigned* __restrict__ maxdb,
    const float* __restrict__ w1, const float* __restrict__ b1,
    const float* __restrict__ w2, const float* __restrict__ b2,
    float* __restrict__ z2o)
{
    int t = threadIdx.x;
    int wave = t >> 6, lane = t & 63;
    long e0 = ((long)blockIdx.x * 4 + wave) * 8;
    float inv = 3.14159265358979323846f / __uint_as_float(*maxdb);
    float w[8];
    #pragma unroll
    for (int c = 0; c < 8; c++)
        w[c] = 0.5f * (cosf(dist[e0 + c] * inv) + 1.0f);
    float2 acc[8];
    #pragma unroll
    for (int c = 0; c < 8; c++) acc[c] = make_float2(0.f, 0.f);
    int col = lane * 2;
    for (int j = 0; j < HIDN; j++) {
        float w1j = w1[j], b1j = b1[j];
        float2 wv = *(const float2*)&w2[j*HIDN + col];
        #pragma unroll
        for (int c = 0; c < 8; c++) {
            float z1 = fmaxf(w[c]*w1j + b1j, 0.f);
            acc[c].x += z1 * wv.x;
            acc[c].y += z1 * wv.y;
        }
    }
    float ba = b2[col], bb = b2[col+1];
    #pragma unroll
    for (int c = 0; c < 8; c++) {
        float2 o;
        o.x = fmaxf(acc[c].x + ba, 0.f);
        o.y = fmaxf(acc[c].y + bb, 0.f);
        *(float2*)&z2o[(size_t)(e0 + c)*HIDN + col] = o;
    }
}

// ---------------- BN column stats (sum, sumsq per feature) ----------------
__global__ __launch_bounds__(256) void k_bnstats(const float* __restrict__ h, float* __restrict__ stats)
{
    int t = threadIdx.x;
    float s = 0.f, ss = 0.f;
    for (size_t i = (size_t)blockIdx.x*256 + t; i < (size_t)NNODE*DD; i += (size_t)gridDim.x*256) {
        float v = h[i]; s += v; ss += v*v;   // i & 31 == t & 31 (stride multiple of 32)
    }
    __shared__ float r0[256], r1[256];
    r0[t] = s; r1[t] = ss;
    __syncthreads();
    if (t < 32) {
        float a = 0.f, b = 0.f;
        for (int k = t; k < 256; k += 32) { a += r0[k]; b += r1[k]; }
        atomicAdd(&stats[t], a);
        atomicAdd(&stats[32 + t], b);
    }
}

// ---------------- fused NNConv layer ----------------
// agg[c] = (sum_e z2[e] (x) hn[n_e]) : W3 + (sum_e hn[n_e]) @ B3, then /denom + conv_b + h
__global__ __launch_bounds__(256) void k_conv(
    const float* __restrict__ hin, float* __restrict__ hout,
    const float* __restrict__ z2, const int* __restrict__ off,
    const int* __restrict__ sN, const int* __restrict__ sE,
    const float* __restrict__ stats,
    const float* __restrict__ bng, const float* __restrict__ bnb,
    const float* __restrict__ w3, const float* __restrict__ b3,
    const float* __restrict__ convb)
{
    __shared__ float s_scale[32], s_shift[32];
    __shared__ __align__(16) float sG[BC][HIDN][DD];   // 48 KB
    __shared__ float s_sum[BC][DD];
    __shared__ float s_red[8][BC][DD];
    int t = threadIdx.x;
    if (t < 32) {
        float mu  = stats[t] * (1.0f/(float)NNODE);
        float var = stats[32+t] * (1.0f/(float)NNODE) - mu*mu;
        float scv = rsqrtf(var + 1e-5f) * bng[t];
        s_scale[t] = scv;
        s_shift[t] = bnb[t] - mu*scv;
    }
    __syncthreads();

    int hr = t >> 1;          // 0..127
    int dh = (t & 1) * 16;    // 0 or 16
    float sc[16], sf[16];
    #pragma unroll
    for (int j = 0; j < 16; j++) { sc[j] = s_scale[dh+j]; sf[j] = s_shift[dh+j]; }

    float g[BC][16];
    #pragma unroll
    for (int c = 0; c < BC; c++)
        #pragma unroll
        for (int j = 0; j < 16; j++) g[c][j] = 0.f;

    for (int c = 0; c < BC; c++) {
        int node = blockIdx.x * BC + c;
        int beg = off[node], end = off[node+1];
        float sh[16];
        #pragma unroll
        for (int j = 0; j < 16; j++) sh[j] = 0.f;
        for (int i = beg; i < end; i++) {
            int n = sN[i];
            int eid = sE[i];
            float zv = z2[(size_t)eid*HIDN + hr];
            const float4* hp = (const float4*)(hin + (size_t)n*DD + dh);
            float hnv[16];
            #pragma unroll
            for (int q = 0; q < 4; q++) {
                float4 x = hp[q];
                hnv[4*q+0] = x.x*sc[4*q+0] + sf[4*q+0];
                hnv[4*q+1] = x.y*sc[4*q+1] + sf[4*q+1];
                hnv[4*q+2] = x.z*sc[4*q+2] + sf[4*q+2];
                hnv[4*q+3] = x.w*sc[4*q+3] + sf[4*q+3];
            }
            #pragma unroll
            for (int j = 0; j < 16; j++) g[c][j] += zv * hnv[j];
            if (t < 2) {
                #pragma unroll
                for (int j = 0; j < 16; j++) sh[j] += hnv[j];
            }
        }
        if (t < 2) {
            #pragma unroll
            for (int j = 0; j < 16; j++) s_sum[c][dh + j] = sh[j];
        }
    }
    // dump G to LDS
    #pragma unroll
    for (int c = 0; c < BC; c++)
        #pragma unroll
        for (int q = 0; q < 4; q++)
            *(float4*)&sG[c][hr][dh + 4*q] =
                make_float4(g[c][4*q], g[c][4*q+1], g[c][4*q+2], g[c][4*q+3]);
    __syncthreads();

    // phase 2: contraction with W3; lane f coalesced on w3, G broadcast from LDS
    int f = t & 31, hg = t >> 5;
    float acc[BC];
    #pragma unroll
    for (int c = 0; c < BC; c++) acc[c] = 0.f;
    const float* w3f = w3 + f;
    for (int hh = hg*16; hh < hg*16 + 16; hh++) {
        const float* wr = w3f + (size_t)hh * (DD*DD);
        #pragma unroll
        for (int d4 = 0; d4 < 8; d4++) {
            float a0 = wr[(d4*4+0)*DD];
            float a1 = wr[(d4*4+1)*DD];
            float a2 = wr[(d4*4+2)*DD];
            float a3 = wr[(d4*4+3)*DD];
            #pragma unroll
            for (int c = 0; c < BC; c++) {
                float4 gv = *(const float4*)&sG[c][hh][d4*4];
                acc[c] += gv.x*a0 + gv.y*a1 + gv.z*a2 + gv.w*a3;
            }
        }
    }
    #pragma unroll
    for (int c = 0; c < BC; c++) s_red[hg][c][f] = acc[c];
    __syncthreads();

    if (t < 32*BC) {
        int c = t >> 5, ff = t & 31;
        float s = 0.f;
        #pragma unroll
        for (int k = 0; k < 8; k++) s += s_red[k][c][ff];
        float bias = 0.f;
        #pragma unroll 8
        for (int d = 0; d < 32; d++) bias += s_sum[c][d] * b3[d*DD + ff];
        int node = blockIdx.x * BC + c;
        int beg = off[node], end = off[node+1];
        float denom = fmaxf((float)(end - beg), 1.0f);
        hout[(size_t)node*DD + ff] = (s + bias) / denom + convb[ff] + hin[(size_t)node*DD + ff];
    }
}

// ---------------- LayerNorm + per-graph decode MLP ----------------
__global__ __launch_bounds__(256) void k_decode(
    const float* __restrict__ h,
    const float* __restrict__ lng, const float* __restrict__ lnb,
    const float* __restrict__ w1, const float* __restrict__ b1,
    const float* __restrict__ w2, const float* __restrict__ b2,
    float* __restrict__ out)
{
    __shared__ float sh[PERG * DD];       // 33 KB
    __shared__ float hid[128], hid2[128];
    int g = blockIdx.x, t = threadIdx.x;
    for (int node = t; node < PERG; node += 256) {
        const float* hr = h + ((size_t)g*PERG + node) * DD;
        float v[32]; float mu = 0.f;
        #pragma unroll
        for (int q = 0; q < 8; q++) {
            float4 x = ((const float4*)hr)[q];
            v[4*q] = x.x; v[4*q+1] = x.y; v[4*q+2] = x.z; v[4*q+3] = x.w;
            mu += x.x + x.y + x.z + x.w;
        }
        mu *= (1.f/32.f);
        float var = 0.f;
        #pragma unroll
        for (int j = 0; j < 32; j++) { float d = v[j]-mu; var += d*d; }
        var *= (1.f/32.f);
        float rs = rsqrtf(var + 1e-5f);
        #pragma unroll
        for (int j = 0; j < 32; j++)
            sh[node*DD + j] = (v[j]-mu)*rs*lng[j] + lnb[j];
    }
    __syncthreads();
    {
        int j = t & 127, half = t >> 7;
        float a = half ? 0.f : b1[j];
        int k0 = half * 4128;
        for (int k = k0; k < k0 + 4128; k++)
            a += sh[k] * w1[(size_t)k*128 + j];
        (half ? hid2 : hid)[j] = a;
    }
    __syncthreads();
    if (t < 128) {
        float v = hid[t] + hid2[t];
        hid[t] = v >= 0.f ? v : 0.2f*v;
    }
    __syncthreads();
    if (t < 128) {
        float a = b2[t];
        #pragma unroll 4
        for (int j = 0; j < 128; j++) a += hid[j]*w2[j*128 + t];
        out[(size_t)g*128 + t] = a;
    }
}

extern "C" void kernel_launch(void* const* d_in, const int* in_sizes, int n_in,
                              void* d_out, int out_size, void* d_ws, size_t ws_size,
                              hipStream_t stream)
{
    const float* pos  = (const float*)d_in[0];
    const float* vel  = (const float*)d_in[1];
    const int*   eidx = (const int*)  d_in[2];
    const float* nw1 = (const float*)d_in[3];  const float* nb1 = (const float*)d_in[4];
    const float* nw2 = (const float*)d_in[5];  const float* nb2 = (const float*)d_in[6];
    const float* vw1 = (const float*)d_in[7];  const float* vb1 = (const float*)d_in[8];
    const float* vw2 = (const float*)d_in[9];  const float* vb2 = (const float*)d_in[10];
    const float* ew1 = (const float*)d_in[11]; const float* eb1 = (const float*)d_in[12];
    const float* ew2 = (const float*)d_in[13]; const float* eb2 = (const float*)d_in[14];
    const float* ew3 = (const float*)d_in[15]; const float* eb3 = (const float*)d_in[16];
    const float* cvb = (const float*)d_in[17];
    const float* b1g = (const float*)d_in[18]; const float* b1b = (const float*)d_in[19];
    const float* b2g = (const float*)d_in[20]; const float* b2b = (const float*)d_in[21];
    const float* lng = (const float*)d_in[22]; const float* lnb = (const float*)d_in[23];
    const float* fw1 = (const float*)d_in[24]; const float* fb1 = (const float*)d_in[25];
    const float* fw2 = (const float*)d_in[26]; const float* fb2 = (const float*)d_in[27];

    char* ws = (char*)d_ws;
    size_t off = 0;
    auto alloc = [&](size_t bytes) -> void* {
        void* p = ws + off;
        off = (off + bytes + 255) & ~(size_t)255;
        return p;
    };
    unsigned* maxd  = (unsigned*)alloc(4);
    float* stats1   = (float*)alloc(64*4);
    float* stats2   = (float*)alloc(64*4);
    int* deg        = (int*)alloc((size_t)NNODE*4);
    int* cursor     = (int*)alloc((size_t)NNODE*4);
    size_t zeroBytes = off;                       // everything above must start at 0
    int* offs       = (int*)alloc((size_t)(NNODE+1)*4);
    int* sN         = (int*)alloc((size_t)NEDGE*4);
    int* sE         = (int*)alloc((size_t)NEDGE*4);
    float* dist     = (float*)alloc((size_t)NEDGE*4);
    float* hA       = (float*)alloc((size_t)NNODE*DD*4);
    float* hB       = (float*)alloc((size_t)NNODE*DD*4);
    float* z2buf    = (float*)alloc((size_t)NEDGE*HIDN*4);

    hipMemsetAsync(d_ws, 0, zeroBytes, stream);

    k_encode<<<(NNODE+255)/256, 256, 0, stream>>>(pos, vel, nw1, nb1, nw2, nb2,
                                                  vw1, vb1, vw2, vb2, hA);
    k_edge1<<<NEDGE/256, 256, 0, stream>>>(pos, eidx, dist, maxd, deg);
    k_scan<<<1, 1024, 0, stream>>>(deg, offs);
    k_scatter<<<NEDGE/256, 256, 0, stream>>>(eidx, offs, cursor, sN, sE);
    k_z2<<<NEDGE/32, 256, 0, stream>>>(dist, maxd, ew1, eb1, ew2, eb2, z2buf);

    k_bnstats<<<64, 256, 0, stream>>>(hA, stats1);
    k_conv<<<NNODE/BC, 256, 0, stream>>>(hA, hB, z2buf, offs, sN, sE,
                                         stats1, b1g, b1b, ew3, eb3, cvb);
    k_bnstats<<<64, 256, 0, stream>>>(hB, stats2);
    k_conv<<<NNODE/BC, 256, 0, stream>>>(hB, hA, z2buf, offs, sN, sE,
                                         stats2, b2g, b2b, ew3, eb3, cvb);

    k_decode<<<NGR, 256, 0, stream>>>(hA, lng, lnb, fw1, fb1, fw2, fb2, (float*)d_out);
}

// Round 2
// 629.662 us; speedup vs baseline: 1.2391x; 1.2391x over previous
//
#include <hip/hip_runtime.h>
#include <hip/hip_bf16.h>

#define NNODE 8256
#define NEDGE 132096
#define DD 32
#define HIDN 128
#define NGR 32
#define PERG 258
#define KPG (PERG*DD)    // 8256 = per-graph flattened K for fc1
#define BC 3             // centers per conv block (8256 = 3*2752)
#define CHUNK 32         // edges staged per LDS round

// ---------------- node encoders: h[N][32] ----------------
__global__ __launch_bounds__(256) void k_encode(
    const float* __restrict__ pos, const float* __restrict__ vel,
    const float* __restrict__ nw1, const float* __restrict__ nb1,
    const float* __restrict__ nw2, const float* __restrict__ nb2,
    const float* __restrict__ vw1, const float* __restrict__ vb1,
    const float* __restrict__ vw2, const float* __restrict__ vb2,
    float* __restrict__ h)
{
    int i = blockIdx.x * 256 + threadIdx.x;
    if (i >= NNODE) return;
    float p0 = pos[i*3], p1 = pos[i*3+1], p2 = pos[i*3+2];
    float v0 = vel[i*3], v1 = vel[i*3+1], v2 = vel[i*3+2];
    float accP[16], accV[16];
    #pragma unroll
    for (int f = 0; f < 16; f++) { accP[f] = nb2[f]; accV[f] = vb2[f]; }
    for (int j = 0; j < HIDN; j++) {
        float hp = p0*nw1[j] + p1*nw1[128+j] + p2*nw1[256+j] + nb1[j];
        hp = hp >= 0.f ? hp : 0.2f*hp;
        float hv = v0*vw1[j] + v1*vw1[128+j] + v2*vw1[256+j] + vb1[j];
        hv = hv >= 0.f ? hv : 0.2f*hv;
        #pragma unroll
        for (int f = 0; f < 16; f++) {
            accP[f] += hp * nw2[j*16+f];
            accV[f] += hv * vw2[j*16+f];
        }
    }
    #pragma unroll
    for (int f = 0; f < 16; f++) {
        h[(size_t)i*DD + f]      = accP[f];
        h[(size_t)i*DD + 16 + f] = accV[f];
    }
}

// ---------------- per-edge dist, max-dist, degree count ----------------
__global__ __launch_bounds__(256) void k_edge1(
    const float* __restrict__ pos, const int* __restrict__ ei,
    float* __restrict__ dist, unsigned* __restrict__ maxd, int* __restrict__ deg)
{
    int e = blockIdx.x * 256 + threadIdx.x;
    float dd = 0.f;
    if (e < NEDGE) {
        int c = ei[e], n = ei[NEDGE + e];
        float dx = pos[c*3]   - pos[n*3];
        float dy = pos[c*3+1] - pos[n*3+1];
        float dz = pos[c*3+2] - pos[n*3+2];
        dd = sqrtf(dx*dx + dy*dy + dz*dz);
        dist[e] = dd;
        atomicAdd(&deg[c], 1);
    }
    #pragma unroll
    for (int o = 32; o > 0; o >>= 1) dd = fmaxf(dd, __shfl_down(dd, o, 64));
    if ((threadIdx.x & 63) == 0) atomicMax(maxd, __float_as_uint(dd));
}

// ---------------- exclusive scan of degrees -> CSR offsets ----------------
__global__ __launch_bounds__(1024) void k_scan(const int* __restrict__ deg, int* __restrict__ off)
{
    __shared__ int s[1024];
    int t = threadIdx.x;
    int base = t * 9;
    int loc[9]; int sum = 0;
    #pragma unroll
    for (int k = 0; k < 9; k++) {
        int i = base + k;
        int v = (i < NNODE) ? deg[i] : 0;
        loc[k] = sum; sum += v;
    }
    s[t] = sum; __syncthreads();
    for (int o = 1; o < 1024; o <<= 1) {
        int v = (t >= o) ? s[t - o] : 0;
        __syncthreads();
        s[t] += v;
        __syncthreads();
    }
    int pre = (t == 0) ? 0 : s[t-1];
    #pragma unroll
    for (int k = 0; k < 9; k++) {
        int i = base + k;
        if (i < NNODE) off[i] = pre + loc[k];
    }
    if (t == 1023) off[NNODE] = s[1023];
}

// ---------------- scatter edges into CSR order ----------------
__global__ __launch_bounds__(256) void k_scatter(
    const int* __restrict__ ei, const int* __restrict__ off,
    int* __restrict__ cursor, int* __restrict__ sN, int* __restrict__ sE)
{
    int e = blockIdx.x * 256 + threadIdx.x;
    if (e >= NEDGE) return;
    int c = ei[e];
    int p = off[c] + atomicAdd(&cursor[c], 1);
    sN[p] = ei[NEDGE + e];
    sE[p] = e;
}

// ---------------- z2 in CSR slot order: z2[i][128] for CSR slot i ----------------
__global__ __launch_bounds__(256) void k_z2(
    const float* __restrict__ dist, const unsigned* __restrict__ maxdb,
    const int* __restrict__ sE,
    const float* __restrict__ w1, const float* __restrict__ b1,
    const float* __restrict__ w2, const float* __restrict__ b2,
    float* __restrict__ z2o)
{
    int t = threadIdx.x;
    int wave = t >> 6, lane = t & 63;
    long i0 = ((long)blockIdx.x * 4 + wave) * 8;
    float inv = 3.14159265358979323846f / __uint_as_float(*maxdb);
    float w[8];
    #pragma unroll
    for (int c = 0; c < 8; c++) {
        int e = sE[i0 + c];
        w[c] = 0.5f * (cosf(dist[e] * inv) + 1.0f);
    }
    float2 acc[8];
    #pragma unroll
    for (int c = 0; c < 8; c++) acc[c] = make_float2(0.f, 0.f);
    int col = lane * 2;
    for (int j = 0; j < HIDN; j++) {
        float w1j = w1[j], b1j = b1[j];
        float2 wv = *(const float2*)&w2[j*HIDN + col];
        #pragma unroll
        for (int c = 0; c < 8; c++) {
            float z1 = fmaxf(w[c]*w1j + b1j, 0.f);
            acc[c].x += z1 * wv.x;
            acc[c].y += z1 * wv.y;
        }
    }
    float ba = b2[col], bb = b2[col+1];
    #pragma unroll
    for (int c = 0; c < 8; c++) {
        float2 o;
        o.x = fmaxf(acc[c].x + ba, 0.f);
        o.y = fmaxf(acc[c].y + bb, 0.f);
        *(float2*)&z2o[(size_t)(i0 + c)*HIDN + col] = o;
    }
}

// ---------------- BN column stats ----------------
__global__ __launch_bounds__(256) void k_bnstats(const float* __restrict__ h, float* __restrict__ stats)
{
    int t = threadIdx.x;
    float s = 0.f, ss = 0.f;
    for (size_t i = (size_t)blockIdx.x*256 + t; i < (size_t)NNODE*DD; i += (size_t)gridDim.x*256) {
        float v = h[i]; s += v; ss += v*v;
    }
    __shared__ float r0[256], r1[256];
    r0[t] = s; r1[t] = ss;
    __syncthreads();
    if (t < 32) {
        float a = 0.f, b = 0.f;
        for (int k = t; k < 256; k += 32) { a += r0[k]; b += r1[k]; }
        atomicAdd(&stats[t], a);
        atomicAdd(&stats[32 + t], b);
    }
}

// ---------------- fused NNConv layer (LDS-staged hn, swizzled sG) ----------------
__global__ __launch_bounds__(256) void k_conv(
    const float* __restrict__ hin, float* __restrict__ hout,
    const float* __restrict__ z2, const int* __restrict__ off,
    const int* __restrict__ sN,
    const float* __restrict__ stats,
    const float* __restrict__ bng, const float* __restrict__ bnb,
    const float* __restrict__ w3, const float* __restrict__ b3,
    const float* __restrict__ convb)
{
    __shared__ float s_scale[DD], s_shift[DD];
    __shared__ float s_sum[BC][DD];
    __shared__ __align__(16) float sG[BC*HIDN*DD];   // 48 KB, XOR-swizzled in d
    __shared__ __align__(16) float s_un[CHUNK*DD];   // sHn (phase1) / s_red (phase3)

    int t = threadIdx.x;
    if (t < DD) {
        float mu  = stats[t] * (1.0f/(float)NNODE);
        float var = stats[DD+t] * (1.0f/(float)NNODE) - mu*mu;
        float scv = rsqrtf(var + 1e-5f) * bng[t];
        s_scale[t] = scv;
        s_shift[t] = bnb[t] - mu*scv;
    }
    if (t < BC*DD) ((float*)s_sum)[t] = 0.f;
    __syncthreads();

    int blockBase = blockIdx.x * BC;
    int o0 = off[blockBase], o1 = off[blockBase+1], o2 = off[blockBase+2], o3 = off[blockBase+3];

    int hr = t >> 1;            // 0..127 (h-row)
    int dh = (t & 1) * 16;      // 0 or 16 (d-half)
    int se = t >> 3;            // staging: edge slot 0..31
    int sq = t & 7;             // staging: quarter 0..7
    float4 sc4 = *(const float4*)&s_scale[sq*4];
    float4 sf4 = *(const float4*)&s_shift[sq*4];

    float g0[16], g1[16], g2[16];
    #pragma unroll
    for (int j = 0; j < 16; j++) { g0[j]=0.f; g1[j]=0.f; g2[j]=0.f; }

    float* sHn = s_un;

    #define ZLD(k) z2[(size_t)(k)*HIDN + hr]
    #define FMA16(G, k, zz) { \
        const float4* hp_ = (const float4*)&sHn[((k) - base)*DD + dh]; \
        float4 xa_ = hp_[0], xb_ = hp_[1], xc_ = hp_[2], xd_ = hp_[3]; \
        G[0]+=zz*xa_.x; G[1]+=zz*xa_.y; G[2]+=zz*xa_.z; G[3]+=zz*xa_.w; \
        G[4]+=zz*xb_.x; G[5]+=zz*xb_.y; G[6]+=zz*xb_.z; G[7]+=zz*xb_.w; \
        G[8]+=zz*xc_.x; G[9]+=zz*xc_.y; G[10]+=zz*xc_.z; G[11]+=zz*xc_.w; \
        G[12]+=zz*xd_.x; G[13]+=zz*xd_.y; G[14]+=zz*xd_.z; G[15]+=zz*xd_.w; }
    #define CENTER_LOOP(G, LO, HI) { \
        int k_ = (LO); \
        for (; k_ + 4 <= (HI); k_ += 4) { \
            float za_=ZLD(k_), zb_=ZLD(k_+1), zc_=ZLD(k_+2), zd_=ZLD(k_+3); \
            FMA16(G, k_,   za_); FMA16(G, k_+1, zb_); \
            FMA16(G, k_+2, zc_); FMA16(G, k_+3, zd_); } \
        for (; k_ < (HI); ++k_) { float za_=ZLD(k_); FMA16(G, k_, za_); } }

    for (int base = o0; base < o3; base += CHUNK) {
        int nE = min(CHUNK, o3 - base);
        if (se < nE) {
            int i = base + se;
            int n = sN[i];
            float4 x = *(const float4*)&hin[(size_t)n*DD + sq*4];
            x.x = x.x*sc4.x + sf4.x; x.y = x.y*sc4.y + sf4.y;
            x.z = x.z*sc4.z + sf4.z; x.w = x.w*sc4.w + sf4.w;
            *(float4*)&sHn[se*DD + sq*4] = x;
            int c = (i >= o1) + (i >= o2);
            atomicAdd(&s_sum[c][sq*4+0], x.x);
            atomicAdd(&s_sum[c][sq*4+1], x.y);
            atomicAdd(&s_sum[c][sq*4+2], x.z);
            atomicAdd(&s_sum[c][sq*4+3], x.w);
        }
        __syncthreads();
        int ce = base + nE;
        {
            int lo = base,          hi = min(ce, o1); CENTER_LOOP(g0, lo, hi);
        }
        {
            int lo = max(base, o1), hi = min(ce, o2); CENTER_LOOP(g1, lo, hi);
        }
        {
            int lo = max(base, o2), hi = ce;          CENTER_LOOP(g2, lo, hi);
        }
        __syncthreads();
    }

    // dump G to swizzled LDS (banks: (dh+j)^(hr&31) -> 2 lanes/bank, free)
    int hsw = hr & 31;
    #pragma unroll
    for (int j = 0; j < 16; j++) {
        int d = dh + j;
        sG[(0*HIDN + hr)*DD + (d ^ hsw)] = g0[j];
        sG[(1*HIDN + hr)*DD + (d ^ hsw)] = g1[j];
        sG[(2*HIDN + hr)*DD + (d ^ hsw)] = g2[j];
    }
    __syncthreads();

    // phase 2: acc[c][f4..f4+3] over (hh,d); w3 coalesced float4, sG conflict-free
    int f4 = (t & 7) * 4;
    int hb = t >> 3;            // 0..31
    float a0[4]={0,0,0,0}, a1[4]={0,0,0,0}, a2[4]={0,0,0,0};
    #pragma unroll
    for (int u = 0; u < 4; u++) {
        int hh = hb*4 + u;
        const float* wr = w3 + (size_t)hh * (DD*DD) + f4;
        int hw = hh & 31;
        #pragma unroll 4
        for (int d = 0; d < DD; d++) {
            float4 wv = *(const float4*)&wr[d*DD];
            int sw = d ^ hw;
            float q0 = sG[(0*HIDN+hh)*DD + sw];
            float q1 = sG[(1*HIDN+hh)*DD + sw];
            float q2 = sG[(2*HIDN+hh)*DD + sw];
            a0[0]+=q0*wv.x; a0[1]+=q0*wv.y; a0[2]+=q0*wv.z; a0[3]+=q0*wv.w;
            a1[0]+=q1*wv.x; a1[1]+=q1*wv.y; a1[2]+=q1*wv.z; a1[3]+=q1*wv.w;
            a2[0]+=q2*wv.x; a2[1]+=q2*wv.y; a2[2]+=q2*wv.z; a2[3]+=q2*wv.w;
        }
    }
    // reduce across the 8 hb-groups within each wave (lane strides 8,16,32)
    #pragma unroll
    for (int s = 8; s < 64; s <<= 1) {
        #pragma unroll
        for (int m = 0; m < 4; m++) {
            a0[m] += __shfl_xor(a0[m], s, 64);
            a1[m] += __shfl_xor(a1[m], s, 64);
            a2[m] += __shfl_xor(a2[m], s, 64);
        }
    }
    float* s_red = s_un;        // [4 waves][BC][DD]
    int wv_ = t >> 6, ln = t & 63;
    if (ln < 8) {
        *(float4*)&s_red[(wv_*BC + 0)*DD + f4] = make_float4(a0[0],a0[1],a0[2],a0[3]);
        *(float4*)&s_red[(wv_*BC + 1)*DD + f4] = make_float4(a1[0],a1[1],a1[2],a1[3]);
        *(float4*)&s_red[(wv_*BC + 2)*DD + f4] = make_float4(a2[0],a2[1],a2[2],a2[3]);
    }
    __syncthreads();

    if (t < BC*DD) {
        int c = t >> 5, f = t & 31;
        float s = s_red[(0*BC+c)*DD+f] + s_red[(1*BC+c)*DD+f]
                + s_red[(2*BC+c)*DD+f] + s_red[(3*BC+c)*DD+f];
        float bias = 0.f;
        #pragma unroll 8
        for (int d = 0; d < DD; d++) bias += s_sum[c][d] * b3[d*DD + f];
        int node = blockBase + c;
        float denom = fmaxf((float)(off[node+1] - off[node]), 1.0f);
        hout[(size_t)node*DD + f] = (s + bias) / denom + convb[f] + hin[(size_t)node*DD + f];
    }
    #undef ZLD
    #undef FMA16
    #undef CENTER_LOOP
}

// ---------------- LayerNorm into hLN ----------------
__global__ __launch_bounds__(256) void k_ln(const float* __restrict__ h,
    const float* __restrict__ lng, const float* __restrict__ lnb, float* __restrict__ hLN)
{
    int i = blockIdx.x * 256 + threadIdx.x;
    if (i >= NNODE) return;
    const float4* hr = (const float4*)(h + (size_t)i*DD);
    float4 v[8];
    float mu = 0.f;
    #pragma unroll
    for (int q = 0; q < 8; q++) { v[q] = hr[q]; mu += v[q].x+v[q].y+v[q].z+v[q].w; }
    mu *= (1.f/32.f);
    float var = 0.f;
    #pragma unroll
    for (int q = 0; q < 8; q++) {
        float d0=v[q].x-mu, d1=v[q].y-mu, d2=v[q].z-mu, d3=v[q].w-mu;
        var += d0*d0 + d1*d1 + d2*d2 + d3*d3;
    }
    var *= (1.f/32.f);
    float rs = rsqrtf(var + 1e-5f);
    float4* o = (float4*)(hLN + (size_t)i*DD);
    #pragma unroll
    for (int q = 0; q < 8; q++) {
        float4 gq = ((const float4*)lng)[q];
        float4 bq = ((const float4*)lnb)[q];
        float4 r;
        r.x = (v[q].x-mu)*rs*gq.x + bq.x;
        r.y = (v[q].y-mu)*rs*gq.y + bq.y;
        r.z = (v[q].z-mu)*rs*gq.z + bq.z;
        r.w = (v[q].w-mu)*rs*gq.w + bq.w;
        o[q] = r;
    }
}

// ---------------- fc1 partial GEMV: grid (32 graphs * 8 k-slices) ----------------
__global__ __launch_bounds__(256) void k_fc1(const float* __restrict__ hLN,
    const float* __restrict__ w1, float* __restrict__ partial)
{
    int g = blockIdx.x >> 3, s = blockIdx.x & 7;
    int j = threadIdx.x & 127, half = threadIdx.x >> 7;
    // slice covers k in [s*1032, (s+1)*1032); half processes float4-groups k0+half*4+m*8
    int k0 = s*1032 + half*4;
    const float* x = hLN + (size_t)g*KPG;
    float a = 0.f;
    #pragma unroll 2
    for (int m = 0; m < 129; m++) {
        int k = k0 + m*8;
        float4 xv = *(const float4*)&x[k];
        const float* wp = w1 + (size_t)k*HIDN + j;
        a += xv.x * wp[0];
        a += xv.y * wp[HIDN];
        a += xv.z * wp[2*HIDN];
        a += xv.w * wp[3*HIDN];
    }
    partial[((size_t)blockIdx.x*2 + half)*HIDN + j] = a;
}

// ---------------- fc2: reduce partials, lrelu, final GEMV ----------------
__global__ __launch_bounds__(128) void k_fc2(const float* __restrict__ partial,
    const float* __restrict__ b1, const float* __restrict__ w2,
    const float* __restrict__ b2, float* __restrict__ out)
{
    __shared__ float hid[128];
    int g = blockIdx.x, t = threadIdx.x;
    float a = b1[t];
    #pragma unroll
    for (int p = 0; p < 16; p++) a += partial[(size_t)(g*16 + p)*HIDN + t];
    a = a >= 0.f ? a : 0.2f*a;
    hid[t] = a;
    __syncthreads();
    float o = b2[t];
    #pragma unroll 4
    for (int j = 0; j < 128; j++) o += hid[j]*w2[j*128 + t];
    out[(size_t)g*128 + t] = o;
}

extern "C" void kernel_launch(void* const* d_in, const int* in_sizes, int n_in,
                              void* d_out, int out_size, void* d_ws, size_t ws_size,
                              hipStream_t stream)
{
    const float* pos  = (const float*)d_in[0];
    const float* vel  = (const float*)d_in[1];
    const int*   eidx = (const int*)  d_in[2];
    const float* nw1 = (const float*)d_in[3];  const float* nb1 = (const float*)d_in[4];
    const float* nw2 = (const float*)d_in[5];  const float* nb2 = (const float*)d_in[6];
    const float* vw1 = (const float*)d_in[7];  const float* vb1 = (const float*)d_in[8];
    const float* vw2 = (const float*)d_in[9];  const float* vb2 = (const float*)d_in[10];
    const float* ew1 = (const float*)d_in[11]; const float* eb1 = (const float*)d_in[12];
    const float* ew2 = (const float*)d_in[13]; const float* eb2 = (const float*)d_in[14];
    const float* ew3 = (const float*)d_in[15]; const float* eb3 = (const float*)d_in[16];
    const float* cvb = (const float*)d_in[17];
    const float* b1g = (const float*)d_in[18]; const float* b1b = (const float*)d_in[19];
    const float* b2g = (const float*)d_in[20]; const float* b2b = (const float*)d_in[21];
    const float* lng = (const float*)d_in[22]; const float* lnb = (const float*)d_in[23];
    const float* fw1 = (const float*)d_in[24]; const float* fb1 = (const float*)d_in[25];
    const float* fw2 = (const float*)d_in[26]; const float* fb2 = (const float*)d_in[27];

    char* ws = (char*)d_ws;
    size_t off = 0;
    auto alloc = [&](size_t bytes) -> void* {
        void* p = ws + off;
        off = (off + bytes + 255) & ~(size_t)255;
        return p;
    };
    unsigned* maxd  = (unsigned*)alloc(4);
    float* stats1   = (float*)alloc(64*4);
    float* stats2   = (float*)alloc(64*4);
    int* deg        = (int*)alloc((size_t)NNODE*4);
    int* cursor     = (int*)alloc((size_t)NNODE*4);
    size_t zeroBytes = off;
    int* offs       = (int*)alloc((size_t)(NNODE+1)*4);
    int* sN         = (int*)alloc((size_t)NEDGE*4);
    int* sE         = (int*)alloc((size_t)NEDGE*4);
    float* dist     = (float*)alloc((size_t)NEDGE*4);
    float* hA       = (float*)alloc((size_t)NNODE*DD*4);
    float* hB       = (float*)alloc((size_t)NNODE*DD*4);
    float* hLN      = (float*)alloc((size_t)NNODE*DD*4);
    float* partial  = (float*)alloc((size_t)NGR*16*HIDN*4);
    float* z2buf    = (float*)alloc((size_t)NEDGE*HIDN*4);

    hipMemsetAsync(d_ws, 0, zeroBytes, stream);

    k_encode<<<(NNODE+255)/256, 256, 0, stream>>>(pos, vel, nw1, nb1, nw2, nb2,
                                                  vw1, vb1, vw2, vb2, hA);
    k_edge1<<<NEDGE/256, 256, 0, stream>>>(pos, eidx, dist, maxd, deg);
    k_scan<<<1, 1024, 0, stream>>>(deg, offs);
    k_scatter<<<NEDGE/256, 256, 0, stream>>>(eidx, offs, cursor, sN, sE);
    k_z2<<<NEDGE/32, 256, 0, stream>>>(dist, maxd, sE, ew1, eb1, ew2, eb2, z2buf);

    k_bnstats<<<64, 256, 0, stream>>>(hA, stats1);
    k_conv<<<NNODE/BC, 256, 0, stream>>>(hA, hB, z2buf, offs, sN,
                                         stats1, b1g, b1b, ew3, eb3, cvb);
    k_bnstats<<<64, 256, 0, stream>>>(hB, stats2);
    k_conv<<<NNODE/BC, 256, 0, stream>>>(hB, hA, z2buf, offs, sN,
                                         stats2, b2g, b2b, ew3, eb3, cvb);

    k_ln<<<(NNODE+255)/256, 256, 0, stream>>>(hA, lng, lnb, hLN);
    k_fc1<<<NGR*8, 256, 0, stream>>>(hLN, fw1, partial);
    k_fc2<<<NGR, 128, 0, stream>>>(partial, fb1, fw2, fb2, (float*)d_out);
}